// Round 12
// baseline (338.601 us; speedup 1.0000x reference)
//
#include <hip/hip_runtime.h>

constexpr int N_NODES = 50000;
constexpr int N_EDGES = 800000;
constexpr int D = 64;

constexpr int NREG = 256;    // destination regions (one gin block each)
constexpr int RSZ = 196;     // nodes per region (256*196 = 50176 >= 50000)
constexpr int EPB = 4096;    // edges per prep block
constexpr int NBINB = 196;   // ceil(800000/4096)
constexpr int CELLCAP = 64;  // per-(region,block) cell cap; mean 16, P(>64) ~ 1e-20
constexpr int RECAP = 4608;  // per-region edge cap; mean 3136, sigma 56

// Workspace layout:
//   cnt2 [NREG*NBINB] ints          at int 0          (200 KB)
//   rbuf [NREG*NBINB*CELLCAP] ints  at int 50176      (12.8 MB, 256B cells)
//   hb   [N_NODES*D] ushorts        at byte 13045760  (6.4 MB)
constexpr int WS_CNT2 = 0;
constexpr int WS_RBUF = 50176;
constexpr size_t WS_HB_BYTE = (size_t)(50176 + (size_t)NREG * NBINB * CELLCAP) * 4;

using vfloat4 = __attribute__((ext_vector_type(4))) float;  // native vec for NT ops

__device__ __forceinline__ ushort to_bf16(float x) {
  unsigned u = __float_as_uint(x);
  u += 0x7FFF + ((u >> 16) & 1);  // RNE
  return (ushort)(u >> 16);
}
__device__ __forceinline__ float bf_lo(unsigned u) {  // low ushort -> float
  return __uint_as_float(u << 16);
}
__device__ __forceinline__ float bf_hi(unsigned u) {  // high ushort -> float
  return __uint_as_float(u & 0xFFFF0000u);
}

// Fused: feat->bf16 conversion slice + edge binning into per-(region,block)
// cells via LDS int cursors (int LDS atomics are cheap; float LDS atomics
// are NOT — R10). Identical to the R8 version (best measured).
__global__ __launch_bounds__(1024) void prep_kernel(
    const float4* __restrict__ feat4, const int* __restrict__ src,
    const int* __restrict__ dst, ushort* __restrict__ hb,
    int* __restrict__ cnt2, unsigned* __restrict__ rbuf) {
  __shared__ int cur[NREG];
  int tid = threadIdx.x, blk = blockIdx.x;
  if (tid < NREG) cur[tid] = 0;

  int e0 = blk * EPB + tid * 4;
  bool valid = (e0 + 4 <= N_EDGES);  // N_EDGES % 4 == 0
  int4 d4 = {0, 0, 0, 0}, s4 = {0, 0, 0, 0};
  if (valid) {
    d4 = *reinterpret_cast<const int4*>(dst + e0);
    s4 = *reinterpret_cast<const int4*>(src + e0);
  }

  // bf16 conversion: 4096 float4 per block (196*4096 >= 800000 float4s).
  int cb = blk * 4096 + tid;
#pragma unroll
  for (int k = 0; k < 4; ++k) {
    int t = cb + k * 1024;
    if (t < N_NODES * D / 4) {
      float4 f = feat4[t];
      ushort4 h;
      h.x = to_bf16(f.x); h.y = to_bf16(f.y);
      h.z = to_bf16(f.z); h.w = to_bf16(f.w);
      *reinterpret_cast<ushort4*>(hb + t * 4) = h;
    }
  }
  __syncthreads();

  if (valid) {
    const int dd[4] = {d4.x, d4.y, d4.z, d4.w};
    const int ss[4] = {s4.x, s4.y, s4.z, s4.w};
#pragma unroll
    for (int k = 0; k < 4; ++k) {
      int r = dd[k] / RSZ;  // magic-mul
      unsigned pk = ((unsigned)(dd[k] - r * RSZ) << 16) | (unsigned)ss[k];
      int p = atomicAdd(&cur[r], 1);
      if (p < CELLCAP)
        rbuf[(size_t)(r * NBINB + blk) * CELLCAP + p] = pk;
    }
  }
  __syncthreads();
  if (tid < NREG) {
    int c = cur[tid];
    cnt2[tid * NBINB + blk] = (c > CELLCAP) ? CELLCAP : c;
  }
}

// One block per region: concat cells -> LDS, counting-sort by local node,
// then per-node gather with 8-LANE groups on bf16 rows (8 x uint4 requests
// per edge — HALF of the previous 16) + eps-residual + Linear with the
// matvec register-blocked over the group's 2 nodes.
__global__ __launch_bounds__(1024) void gin_kernel(
    const float* __restrict__ feat, const ushort* __restrict__ hb,
    const float* __restrict__ W, const float* __restrict__ b,
    const float* __restrict__ eps, const int* __restrict__ cnt2,
    const unsigned* __restrict__ rbuf, float* __restrict__ out) {
  __shared__ float Wt[D * D];       // 16 KB: Wt[i*64+o] = W[o*64+i]
  __shared__ unsigned ebuf[RECAP];  // 18 KB
  __shared__ ushort sorted[RECAP];  // 9 KB
  __shared__ int cellstart[NBINB + 1];
  __shared__ int hist[RSZ], nstart[RSZ + 1], cursor[RSZ];
  __shared__ int scan_tmp[256];

  int tid = threadIdx.x, r = blockIdx.x;
  for (int q = tid; q < D * D; q += 1024) Wt[q] = W[((q & 63) << 6) + (q >> 6)];
  if (tid < RSZ) hist[tid] = 0;

  int c = (tid < NBINB) ? cnt2[r * NBINB + tid] : 0;
  if (tid < 256) scan_tmp[tid] = c;
  __syncthreads();
  for (int ofs = 1; ofs < 256; ofs <<= 1) {
    int v = 0;
    if (tid < 256 && tid >= ofs) v = scan_tmp[tid - ofs];
    __syncthreads();
    if (tid < 256) scan_tmp[tid] += v;
    __syncthreads();
  }
  if (tid < NBINB) cellstart[tid] = scan_tmp[tid] - c;
  if (tid == NBINB - 1) cellstart[NBINB] = scan_tmp[tid];
  __syncthreads();
  int T = cellstart[NBINB];
  if (T > RECAP) T = RECAP;

  {  // Concatenate cells into ebuf: 4 threads per cell, uint4 loads.
    int cell = tid >> 2, sub = tid & 3;
    if (cell < NBINB) {
      int cs = cellstart[cell];
      int cc = cellstart[cell + 1] - cs;
      const unsigned* cp = rbuf + (size_t)(r * NBINB + cell) * CELLCAP;
      for (int i = sub * 4; i < cc; i += 16) {
        uint4 v = *reinterpret_cast<const uint4*>(cp + i);
        if (cs + i + 0 < T && i + 0 < cc) ebuf[cs + i + 0] = v.x;
        if (cs + i + 1 < T && i + 1 < cc) ebuf[cs + i + 1] = v.y;
        if (cs + i + 2 < T && i + 2 < cc) ebuf[cs + i + 2] = v.z;
        if (cs + i + 3 < T && i + 3 < cc) ebuf[cs + i + 3] = v.w;
      }
    }
  }
  __syncthreads();

  // Counting sort by local node (int LDS atomics).
  for (int e = tid; e < T; e += 1024) atomicAdd(&hist[ebuf[e] >> 16], 1);
  __syncthreads();
  if (tid < 256) scan_tmp[tid] = (tid < RSZ) ? hist[tid] : 0;
  __syncthreads();
  for (int ofs = 1; ofs < 256; ofs <<= 1) {
    int v = 0;
    if (tid < 256 && tid >= ofs) v = scan_tmp[tid - ofs];
    __syncthreads();
    if (tid < 256) scan_tmp[tid] += v;
    __syncthreads();
  }
  if (tid < RSZ) {
    int ex = scan_tmp[tid] - hist[tid];
    nstart[tid] = ex;
    cursor[tid] = ex;
  }
  if (tid == RSZ - 1) nstart[RSZ] = scan_tmp[tid];
  __syncthreads();
  for (int e = tid; e < T; e += 1024) {
    unsigned pk = ebuf[e];
    int p = atomicAdd(&cursor[pk >> 16], 1);
    sorted[p] = (ushort)(pk & 0xFFFFu);
  }
  __syncthreads();

  // 128 groups x 8 lanes; lane owns feature slots j8..j8+7 (16 B of bf16).
  int g = tid >> 3, j8 = (tid & 7) << 3;
  float s = 1.0f + eps[0];

  int n0 = g, n1 = g + 128;
  int node0 = r * RSZ + n0, node1 = r * RSZ + n1;
  bool valid0 = (n0 < RSZ) && (node0 < N_NODES);
  bool valid1 = (n1 < RSZ) && (node1 < N_NODES);

  float acc0[8] = {0, 0, 0, 0, 0, 0, 0, 0};
  float acc1[8] = {0, 0, 0, 0, 0, 0, 0, 0};

#pragma unroll
  for (int which = 0; which < 2; ++which) {
    bool valid = which ? valid1 : valid0;
    if (!valid) continue;  // group-uniform
    int n = which ? n1 : n0;
    int node = which ? node1 : node0;
    float* acc = which ? acc1 : acc0;

    {  // self term: 8 fp32 = two float4 loads
      const float4 fa = *reinterpret_cast<const float4*>(feat + (node << 6) + j8);
      const float4 fb = *reinterpret_cast<const float4*>(feat + (node << 6) + j8 + 4);
      acc[0] = s * fa.x; acc[1] = s * fa.y; acc[2] = s * fa.z; acc[3] = s * fa.w;
      acc[4] = s * fb.x; acc[5] = s * fb.y; acc[6] = s * fb.z; acc[7] = s * fb.w;
    }
    int e = nstart[n], e1 = nstart[n + 1];
    for (; e + 8 <= e1; e += 8) {
      uint4 h[8];
#pragma unroll
      for (int k = 0; k < 8; ++k) {
        int sn = sorted[e + k];
        h[k] = *reinterpret_cast<const uint4*>(hb + (sn << 6) + j8);
      }
#pragma unroll
      for (int k = 0; k < 8; ++k) {
        acc[0] += bf_lo(h[k].x); acc[1] += bf_hi(h[k].x);
        acc[2] += bf_lo(h[k].y); acc[3] += bf_hi(h[k].y);
        acc[4] += bf_lo(h[k].z); acc[5] += bf_hi(h[k].z);
        acc[6] += bf_lo(h[k].w); acc[7] += bf_hi(h[k].w);
      }
    }
    for (; e < e1; ++e) {
      int sn = sorted[e];
      uint4 hv = *reinterpret_cast<const uint4*>(hb + (sn << 6) + j8);
      acc[0] += bf_lo(hv.x); acc[1] += bf_hi(hv.x);
      acc[2] += bf_lo(hv.y); acc[3] += bf_hi(hv.y);
      acc[4] += bf_lo(hv.z); acc[5] += bf_hi(hv.z);
      acc[6] += bf_lo(hv.w); acc[7] += bf_hi(hv.w);
    }
  }

  // Joint matvec for the node pair: one Wt pass amortized over 2 nodes.
  if (valid0) {
    float res0[8], res1[8];
    {
      const float4 ba = *reinterpret_cast<const float4*>(b + j8);
      const float4 bb = *reinterpret_cast<const float4*>(b + j8 + 4);
      res0[0] = ba.x; res0[1] = ba.y; res0[2] = ba.z; res0[3] = ba.w;
      res0[4] = bb.x; res0[5] = bb.y; res0[6] = bb.z; res0[7] = bb.w;
#pragma unroll
      for (int k = 0; k < 8; ++k) res1[k] = res0[k];
    }
#pragma unroll
    for (int i = 0; i < D; ++i) {
      int srcl = i >> 3, k = i & 7;
      float r0 = __shfl(acc0[k], srcl, 8);  // rst[n0][i]
      float r1 = __shfl(acc1[k], srcl, 8);  // rst[n1][i]
      const float4 wa = *reinterpret_cast<const float4*>(Wt + i * D + j8);
      const float4 wb = *reinterpret_cast<const float4*>(Wt + i * D + j8 + 4);
      res0[0] += r0 * wa.x; res0[1] += r0 * wa.y;
      res0[2] += r0 * wa.z; res0[3] += r0 * wa.w;
      res0[4] += r0 * wb.x; res0[5] += r0 * wb.y;
      res0[6] += r0 * wb.z; res0[7] += r0 * wb.w;
      res1[0] += r1 * wa.x; res1[1] += r1 * wa.y;
      res1[2] += r1 * wa.z; res1[3] += r1 * wa.w;
      res1[4] += r1 * wb.x; res1[5] += r1 * wb.y;
      res1[6] += r1 * wb.z; res1[7] += r1 * wb.w;
    }
    {
      vfloat4 v;
      v.x = res0[0]; v.y = res0[1]; v.z = res0[2]; v.w = res0[3];
      __builtin_nontemporal_store(v, reinterpret_cast<vfloat4*>(out + (node0 << 6) + j8));
      v.x = res0[4]; v.y = res0[5]; v.z = res0[6]; v.w = res0[7];
      __builtin_nontemporal_store(v, reinterpret_cast<vfloat4*>(out + (node0 << 6) + j8 + 4));
    }
    if (valid1) {
      vfloat4 v;
      v.x = res1[0]; v.y = res1[1]; v.z = res1[2]; v.w = res1[3];
      __builtin_nontemporal_store(v, reinterpret_cast<vfloat4*>(out + (node1 << 6) + j8));
      v.x = res1[4]; v.y = res1[5]; v.z = res1[6]; v.w = res1[7];
      __builtin_nontemporal_store(v, reinterpret_cast<vfloat4*>(out + (node1 << 6) + j8 + 4));
    }
  }
}

extern "C" void kernel_launch(void* const* d_in, const int* in_sizes, int n_in,
                              void* d_out, int out_size, void* d_ws, size_t ws_size,
                              hipStream_t stream) {
  const float* feat = (const float*)d_in[0];
  const float* W    = (const float*)d_in[1];
  const float* b    = (const float*)d_in[2];
  const float* eps  = (const float*)d_in[3];
  const int*   src  = (const int*)d_in[4];
  const int*   dst  = (const int*)d_in[5];
  float* out = (float*)d_out;

  int* ws = (int*)d_ws;
  int* cnt2      = ws + WS_CNT2;
  unsigned* rbuf = (unsigned*)(ws + WS_RBUF);
  ushort* hb     = (ushort*)((char*)d_ws + WS_HB_BYTE);

  hipLaunchKernelGGL(prep_kernel, dim3(NBINB), dim3(1024), 0, stream,
                     (const float4*)feat, src, dst, hb, cnt2, rbuf);
  hipLaunchKernelGGL(gin_kernel, dim3(NREG), dim3(1024), 0, stream,
                     feat, hb, W, b, eps, cnt2, rbuf, out);
}

// Round 13
// 110.964 us; speedup vs baseline: 3.0515x; 3.0515x over previous
//
#include <hip/hip_runtime.h>

constexpr int N_NODES = 50000;
constexpr int N_EDGES = 800000;
constexpr int D = 64;

constexpr int NREG = 256;    // destination regions (one gin block each)
constexpr int RSZ = 196;     // nodes per region (256*196 = 50176 >= 50000)
constexpr int EPB = 4096;    // edges per prep block
constexpr int NBINB = 196;   // ceil(800000/4096)
constexpr int CELLCAP = 64;  // per-(region,block) cell cap; mean 16, P(>64) ~ 1e-20
constexpr int RECAP = 4608;  // per-region edge cap; mean 3136, sigma 56

// Workspace layout:
//   cnt2 [NREG*NBINB] ints          at int 0          (200 KB)
//   rbuf [NREG*NBINB*CELLCAP] ints  at int 50176      (12.8 MB, 256B cells)
//   hb   [N_NODES*D] ushorts        at byte 13045760  (6.4 MB)
constexpr int WS_CNT2 = 0;
constexpr int WS_RBUF = 50176;
constexpr size_t WS_HB_BYTE = (size_t)(50176 + (size_t)NREG * NBINB * CELLCAP) * 4;

__device__ __forceinline__ ushort to_bf16(float x) {
  unsigned u = __float_as_uint(x);
  u += 0x7FFF + ((u >> 16) & 1);  // RNE
  return (ushort)(u >> 16);
}
__device__ __forceinline__ float bf_lo(unsigned u) {
  return __uint_as_float(u << 16);
}
__device__ __forceinline__ float bf_hi(unsigned u) {
  return __uint_as_float(u & 0xFFFF0000u);
}

// Fused: feat->bf16 conversion slice + edge binning into per-(region,block)
// cells via LDS int cursors. EXACT copy of the R8 kernel (best measured).
__global__ __launch_bounds__(1024) void prep_kernel(
    const float4* __restrict__ feat4, const int* __restrict__ src,
    const int* __restrict__ dst, ushort* __restrict__ hb,
    int* __restrict__ cnt2, unsigned* __restrict__ rbuf) {
  __shared__ int cur[NREG];
  int tid = threadIdx.x, blk = blockIdx.x;
  if (tid < NREG) cur[tid] = 0;

  int e0 = blk * EPB + tid * 4;
  bool valid = (e0 + 4 <= N_EDGES);  // N_EDGES % 4 == 0
  int4 d4 = {0, 0, 0, 0}, s4 = {0, 0, 0, 0};
  if (valid) {
    d4 = *reinterpret_cast<const int4*>(dst + e0);
    s4 = *reinterpret_cast<const int4*>(src + e0);
  }

  // bf16 conversion: 4096 float4 per block (196*4096 >= 800000 float4s).
  int cb = blk * 4096 + tid;
#pragma unroll
  for (int k = 0; k < 4; ++k) {
    int t = cb + k * 1024;
    if (t < N_NODES * D / 4) {
      float4 f = feat4[t];
      ushort4 h;
      h.x = to_bf16(f.x); h.y = to_bf16(f.y);
      h.z = to_bf16(f.z); h.w = to_bf16(f.w);
      *reinterpret_cast<ushort4*>(hb + t * 4) = h;
    }
  }
  __syncthreads();

  if (valid) {
    const int dd[4] = {d4.x, d4.y, d4.z, d4.w};
    const int ss[4] = {s4.x, s4.y, s4.z, s4.w};
#pragma unroll
    for (int k = 0; k < 4; ++k) {
      int r = dd[k] / RSZ;  // magic-mul
      unsigned pk = ((unsigned)(dd[k] - r * RSZ) << 16) | (unsigned)ss[k];
      int p = atomicAdd(&cur[r], 1);
      if (p < CELLCAP)
        rbuf[(size_t)(r * NBINB + blk) * CELLCAP + p] = pk;
    }
  }
  __syncthreads();
  if (tid < NREG) {
    int c = cur[tid];
    cnt2[tid * NBINB + blk] = (c > CELLCAP) ? CELLCAP : c;
  }
}

// One block per region: concat cells -> LDS, counting-sort by local node
// (prologue identical to R8), then per-node gather with 8-LANE groups on
// bf16 rows (one uint4 per lane => 8 requests/edge, half of R8) +
// eps-residual + Linear. No local-array pointer selects (R12 spill bug).
__global__ __launch_bounds__(1024) void gin_kernel(
    const float* __restrict__ feat, const ushort* __restrict__ hb,
    const float* __restrict__ W, const float* __restrict__ b,
    const float* __restrict__ eps, const int* __restrict__ cnt2,
    const unsigned* __restrict__ rbuf, float* __restrict__ out) {
  __shared__ float Wt[D * D];       // 16 KB: Wt[i*64+o] = W[o*64+i]
  __shared__ unsigned ebuf[RECAP];  // 18 KB
  __shared__ ushort sorted[RECAP];  // 9 KB
  __shared__ int cellstart[NBINB + 1];
  __shared__ int hist[RSZ], nstart[RSZ + 1], cursor[RSZ];
  __shared__ int scan_tmp[256];

  int tid = threadIdx.x, r = blockIdx.x;
  for (int q = tid; q < D * D; q += 1024) Wt[q] = W[((q & 63) << 6) + (q >> 6)];
  if (tid < RSZ) hist[tid] = 0;

  int c = (tid < NBINB) ? cnt2[r * NBINB + tid] : 0;
  if (tid < 256) scan_tmp[tid] = c;
  __syncthreads();
  for (int ofs = 1; ofs < 256; ofs <<= 1) {
    int v = 0;
    if (tid < 256 && tid >= ofs) v = scan_tmp[tid - ofs];
    __syncthreads();
    if (tid < 256) scan_tmp[tid] += v;
    __syncthreads();
  }
  if (tid < NBINB) cellstart[tid] = scan_tmp[tid] - c;
  if (tid == NBINB - 1) cellstart[NBINB] = scan_tmp[tid];
  __syncthreads();
  int T = cellstart[NBINB];
  if (T > RECAP) T = RECAP;

  {  // Concatenate cells into ebuf: 4 threads per cell, uint4 loads.
    int cell = tid >> 2, sub = tid & 3;
    if (cell < NBINB) {
      int cs = cellstart[cell];
      int cc = cellstart[cell + 1] - cs;
      const unsigned* cp = rbuf + (size_t)(r * NBINB + cell) * CELLCAP;
      for (int i = sub * 4; i < cc; i += 16) {
        uint4 v = *reinterpret_cast<const uint4*>(cp + i);
        if (cs + i + 0 < T && i + 0 < cc) ebuf[cs + i + 0] = v.x;
        if (cs + i + 1 < T && i + 1 < cc) ebuf[cs + i + 1] = v.y;
        if (cs + i + 2 < T && i + 2 < cc) ebuf[cs + i + 2] = v.z;
        if (cs + i + 3 < T && i + 3 < cc) ebuf[cs + i + 3] = v.w;
      }
    }
  }
  __syncthreads();

  // Counting sort by local node (int LDS atomics).
  for (int e = tid; e < T; e += 1024) atomicAdd(&hist[ebuf[e] >> 16], 1);
  __syncthreads();
  if (tid < 256) scan_tmp[tid] = (tid < RSZ) ? hist[tid] : 0;
  __syncthreads();
  for (int ofs = 1; ofs < 256; ofs <<= 1) {
    int v = 0;
    if (tid < 256 && tid >= ofs) v = scan_tmp[tid - ofs];
    __syncthreads();
    if (tid < 256) scan_tmp[tid] += v;
    __syncthreads();
  }
  if (tid < RSZ) {
    int ex = scan_tmp[tid] - hist[tid];
    nstart[tid] = ex;
    cursor[tid] = ex;
  }
  if (tid == RSZ - 1) nstart[RSZ] = scan_tmp[tid];
  __syncthreads();
  for (int e = tid; e < T; e += 1024) {
    unsigned pk = ebuf[e];
    int p = atomicAdd(&cursor[pk >> 16], 1);
    sorted[p] = (ushort)(pk & 0xFFFFu);
  }
  __syncthreads();

  // 128 groups x 8 lanes; lane owns feature slots j8..j8+7 (one uint4 of hb).
  int g = tid >> 3, j8 = (tid & 7) << 3;
  float s = 1.0f + eps[0];

  for (int n = g; n < RSZ; n += 128) {  // 2 iterations
    int node = r * RSZ + n;
    if (node >= N_NODES) continue;  // group-uniform

    float acc[8];
    {  // self term in fp32 (exact residual path)
      const float4 fa = *reinterpret_cast<const float4*>(feat + (node << 6) + j8);
      const float4 fb = *reinterpret_cast<const float4*>(feat + (node << 6) + j8 + 4);
      acc[0] = s * fa.x; acc[1] = s * fa.y; acc[2] = s * fa.z; acc[3] = s * fa.w;
      acc[4] = s * fb.x; acc[5] = s * fb.y; acc[6] = s * fb.z; acc[7] = s * fb.w;
    }

    int e = nstart[n], e1 = nstart[n + 1];
    for (; e + 4 <= e1; e += 4) {
      int i0 = sorted[e + 0], i1 = sorted[e + 1], i2 = sorted[e + 2], i3 = sorted[e + 3];
      const uint4 h0 = *reinterpret_cast<const uint4*>(hb + (i0 << 6) + j8);
      const uint4 h1 = *reinterpret_cast<const uint4*>(hb + (i1 << 6) + j8);
      const uint4 h2 = *reinterpret_cast<const uint4*>(hb + (i2 << 6) + j8);
      const uint4 h3 = *reinterpret_cast<const uint4*>(hb + (i3 << 6) + j8);
      acc[0] += (bf_lo(h0.x) + bf_lo(h1.x)) + (bf_lo(h2.x) + bf_lo(h3.x));
      acc[1] += (bf_hi(h0.x) + bf_hi(h1.x)) + (bf_hi(h2.x) + bf_hi(h3.x));
      acc[2] += (bf_lo(h0.y) + bf_lo(h1.y)) + (bf_lo(h2.y) + bf_lo(h3.y));
      acc[3] += (bf_hi(h0.y) + bf_hi(h1.y)) + (bf_hi(h2.y) + bf_hi(h3.y));
      acc[4] += (bf_lo(h0.z) + bf_lo(h1.z)) + (bf_lo(h2.z) + bf_lo(h3.z));
      acc[5] += (bf_hi(h0.z) + bf_hi(h1.z)) + (bf_hi(h2.z) + bf_hi(h3.z));
      acc[6] += (bf_lo(h0.w) + bf_lo(h1.w)) + (bf_lo(h2.w) + bf_lo(h3.w));
      acc[7] += (bf_hi(h0.w) + bf_hi(h1.w)) + (bf_hi(h2.w) + bf_hi(h3.w));
    }
    for (; e < e1; ++e) {
      int sn = sorted[e];
      const uint4 hv = *reinterpret_cast<const uint4*>(hb + (sn << 6) + j8);
      acc[0] += bf_lo(hv.x); acc[1] += bf_hi(hv.x);
      acc[2] += bf_lo(hv.y); acc[3] += bf_hi(hv.y);
      acc[4] += bf_lo(hv.z); acc[5] += bf_hi(hv.z);
      acc[6] += bf_lo(hv.w); acc[7] += bf_hi(hv.w);
    }

    // Matvec: feature i lives in lane (i>>3), slot (i&7) — both constant
    // under full unroll, so acc stays in registers (SROA-safe).
    float res[8];
    {
      const float4 ba = *reinterpret_cast<const float4*>(b + j8);
      const float4 bb = *reinterpret_cast<const float4*>(b + j8 + 4);
      res[0] = ba.x; res[1] = ba.y; res[2] = ba.z; res[3] = ba.w;
      res[4] = bb.x; res[5] = bb.y; res[6] = bb.z; res[7] = bb.w;
    }
#pragma unroll
    for (int i = 0; i < D; ++i) {
      float rv = __shfl(acc[i & 7], i >> 3, 8);  // rst[node][i]
      const float4 wa = *reinterpret_cast<const float4*>(Wt + i * D + j8);
      const float4 wb = *reinterpret_cast<const float4*>(Wt + i * D + j8 + 4);
      res[0] += rv * wa.x; res[1] += rv * wa.y;
      res[2] += rv * wa.z; res[3] += rv * wa.w;
      res[4] += rv * wb.x; res[5] += rv * wb.y;
      res[6] += rv * wb.z; res[7] += rv * wb.w;
    }
    float4 o0, o1;
    o0.x = res[0]; o0.y = res[1]; o0.z = res[2]; o0.w = res[3];
    o1.x = res[4]; o1.y = res[5]; o1.z = res[6]; o1.w = res[7];
    *reinterpret_cast<float4*>(out + (node << 6) + j8) = o0;
    *reinterpret_cast<float4*>(out + (node << 6) + j8 + 4) = o1;
  }
}

extern "C" void kernel_launch(void* const* d_in, const int* in_sizes, int n_in,
                              void* d_out, int out_size, void* d_ws, size_t ws_size,
                              hipStream_t stream) {
  const float* feat = (const float*)d_in[0];
  const float* W    = (const float*)d_in[1];
  const float* b    = (const float*)d_in[2];
  const float* eps  = (const float*)d_in[3];
  const int*   src  = (const int*)d_in[4];
  const int*   dst  = (const int*)d_in[5];
  float* out = (float*)d_out;

  int* ws = (int*)d_ws;
  int* cnt2      = ws + WS_CNT2;
  unsigned* rbuf = (unsigned*)(ws + WS_RBUF);
  ushort* hb     = (ushort*)((char*)d_ws + WS_HB_BYTE);

  hipLaunchKernelGGL(prep_kernel, dim3(NBINB), dim3(1024), 0, stream,
                     (const float4*)feat, src, dst, hb, cnt2, rbuf);
  hipLaunchKernelGGL(gin_kernel, dim3(NREG), dim3(1024), 0, stream,
                     feat, hb, W, b, eps, cnt2, rbuf, out);
}

// Round 14
// 110.856 us; speedup vs baseline: 3.0544x; 1.0010x over previous
//
#include <hip/hip_runtime.h>

constexpr int N_NODES = 50000;
constexpr int N_EDGES = 800000;
constexpr int D = 64;

constexpr int NREG = 256;    // destination regions (one gin block each)
constexpr int RSZ = 196;     // nodes per region (256*196 = 50176 >= 50000)
constexpr int EPB = 4096;    // edges per prep block
constexpr int NBINB = 196;   // ceil(800000/4096)
constexpr int CELLCAP = 64;  // per-(region,block) cell cap; mean 16, P(>64) ~ 1e-20
constexpr int RECAP = 4608;  // per-region edge cap; mean 3136, sigma 56

// Workspace layout:
//   cnt2 [NREG*NBINB] ints          at int 0          (200 KB)
//   rbuf [NREG*NBINB*CELLCAP] ints  at int 50176      (12.8 MB, 256B cells)
//   hb   [N_NODES*D] ushorts        at byte 13045760  (6.4 MB)
constexpr int WS_CNT2 = 0;
constexpr int WS_RBUF = 50176;
constexpr size_t WS_HB_BYTE = (size_t)(50176 + (size_t)NREG * NBINB * CELLCAP) * 4;

__device__ __forceinline__ ushort to_bf16(float x) {
  unsigned u = __float_as_uint(x);
  u += 0x7FFF + ((u >> 16) & 1);  // RNE
  return (ushort)(u >> 16);
}
__device__ __forceinline__ float bf_lo(unsigned u) {
  return __uint_as_float(u << 16);
}
__device__ __forceinline__ float bf_hi(unsigned u) {
  return __uint_as_float(u & 0xFFFF0000u);
}

// Fused: feat->bf16 conversion slice + edge binning into per-(region,block)
// cells via LDS int cursors. EXACT copy of the R8/R13 kernel (best measured).
__global__ __launch_bounds__(1024) void prep_kernel(
    const float4* __restrict__ feat4, const int* __restrict__ src,
    const int* __restrict__ dst, ushort* __restrict__ hb,
    int* __restrict__ cnt2, unsigned* __restrict__ rbuf) {
  __shared__ int cur[NREG];
  int tid = threadIdx.x, blk = blockIdx.x;
  if (tid < NREG) cur[tid] = 0;

  int e0 = blk * EPB + tid * 4;
  bool valid = (e0 + 4 <= N_EDGES);  // N_EDGES % 4 == 0
  int4 d4 = {0, 0, 0, 0}, s4 = {0, 0, 0, 0};
  if (valid) {
    d4 = *reinterpret_cast<const int4*>(dst + e0);
    s4 = *reinterpret_cast<const int4*>(src + e0);
  }

  // bf16 conversion: 4096 float4 per block (196*4096 >= 800000 float4s).
  int cb = blk * 4096 + tid;
#pragma unroll
  for (int k = 0; k < 4; ++k) {
    int t = cb + k * 1024;
    if (t < N_NODES * D / 4) {
      float4 f = feat4[t];
      ushort4 h;
      h.x = to_bf16(f.x); h.y = to_bf16(f.y);
      h.z = to_bf16(f.z); h.w = to_bf16(f.w);
      *reinterpret_cast<ushort4*>(hb + t * 4) = h;
    }
  }
  __syncthreads();

  if (valid) {
    const int dd[4] = {d4.x, d4.y, d4.z, d4.w};
    const int ss[4] = {s4.x, s4.y, s4.z, s4.w};
#pragma unroll
    for (int k = 0; k < 4; ++k) {
      int r = dd[k] / RSZ;  // magic-mul
      unsigned pk = ((unsigned)(dd[k] - r * RSZ) << 16) | (unsigned)ss[k];
      int p = atomicAdd(&cur[r], 1);
      if (p < CELLCAP)
        rbuf[(size_t)(r * NBINB + blk) * CELLCAP + p] = pk;
    }
  }
  __syncthreads();
  if (tid < NREG) {
    int c = cur[tid];
    cnt2[tid * NBINB + blk] = (c > CELLCAP) ? CELLCAP : c;
  }
}

// One block per region. Same structure as R13 but the two 256-wide LDS scans
// are replaced with wave-level shfl_up scans + 4-entry cross-wave fixup:
// barrier count drops ~40 -> 7. Gather unrolled 8-deep.
__global__ __launch_bounds__(1024) void gin_kernel(
    const float* __restrict__ feat, const ushort* __restrict__ hb,
    const float* __restrict__ W, const float* __restrict__ b,
    const float* __restrict__ eps, const int* __restrict__ cnt2,
    const unsigned* __restrict__ rbuf, float* __restrict__ out) {
  __shared__ float Wt[D * D];       // 16 KB: Wt[i*64+o] = W[o*64+i]
  __shared__ unsigned ebuf[RECAP];  // 18 KB
  __shared__ ushort sorted[RECAP];  // 9 KB
  __shared__ int cellstart[NBINB + 1];
  __shared__ int hist[RSZ], nstart[RSZ + 1], cursor[RSZ];
  __shared__ int wsum[4], wsum2[4];

  int tid = threadIdx.x, r = blockIdx.x;
  int lane = tid & 63, wv = tid >> 6;
  for (int q = tid; q < D * D; q += 1024) Wt[q] = W[((q & 63) << 6) + (q >> 6)];
  if (tid < RSZ) hist[tid] = 0;

  // ---- scan 1: 196 cell counts, wave-level (no barriers inside) ----
  int c = (tid < NBINB) ? cnt2[r * NBINB + tid] : 0;
  int inc = c;
#pragma unroll
  for (int dlt = 1; dlt < 64; dlt <<= 1) {
    int t = __shfl_up(inc, (unsigned)dlt, 64);
    if (lane >= dlt) inc += t;
  }
  if (tid < 256 && lane == 63) wsum[wv] = inc;
  __syncthreads();  // B1
  if (tid < 256) {
    int prefix = inc - c;
    if (wv > 0) prefix += wsum[0];
    if (wv > 1) prefix += wsum[1];
    if (wv > 2) prefix += wsum[2];
    if (tid < NBINB) cellstart[tid] = prefix;
  }
  if (tid == 0) cellstart[NBINB] = wsum[0] + wsum[1] + wsum[2] + wsum[3];
  __syncthreads();  // B2
  int T = cellstart[NBINB];
  if (T > RECAP) T = RECAP;  // statistically impossible

  {  // Concatenate cells into ebuf: 4 threads per cell, uint4 loads.
    int cell = tid >> 2, sub = tid & 3;
    if (cell < NBINB) {
      int cs = cellstart[cell];
      int cc = cellstart[cell + 1] - cs;
      const unsigned* cp = rbuf + (size_t)(r * NBINB + cell) * CELLCAP;
      for (int i = sub * 4; i < cc; i += 16) {
        uint4 v = *reinterpret_cast<const uint4*>(cp + i);
        if (cs + i + 0 < T && i + 0 < cc) ebuf[cs + i + 0] = v.x;
        if (cs + i + 1 < T && i + 1 < cc) ebuf[cs + i + 1] = v.y;
        if (cs + i + 2 < T && i + 2 < cc) ebuf[cs + i + 2] = v.z;
        if (cs + i + 3 < T && i + 3 < cc) ebuf[cs + i + 3] = v.w;
      }
    }
  }
  __syncthreads();  // B3

  // Histogram by local node (int LDS atomics — cheap).
  for (int e = tid; e < T; e += 1024) atomicAdd(&hist[ebuf[e] >> 16], 1);
  __syncthreads();  // B4

  // ---- scan 2: 196 node counts, wave-level ----
  int h = (tid < RSZ) ? hist[tid] : 0;
  int inc2 = h;
#pragma unroll
  for (int dlt = 1; dlt < 64; dlt <<= 1) {
    int t = __shfl_up(inc2, (unsigned)dlt, 64);
    if (lane >= dlt) inc2 += t;
  }
  if (tid < 256 && lane == 63) wsum2[wv] = inc2;
  __syncthreads();  // B5
  if (tid < 256) {
    int prefix = inc2 - h;
    if (wv > 0) prefix += wsum2[0];
    if (wv > 1) prefix += wsum2[1];
    if (wv > 2) prefix += wsum2[2];
    if (tid < RSZ) {
      nstart[tid] = prefix;
      cursor[tid] = prefix;
    }
  }
  if (tid == 0) nstart[RSZ] = wsum2[0] + wsum2[1] + wsum2[2] + wsum2[3];
  __syncthreads();  // B6
  for (int e = tid; e < T; e += 1024) {
    unsigned pk = ebuf[e];
    int p = atomicAdd(&cursor[pk >> 16], 1);
    sorted[p] = (ushort)(pk & 0xFFFFu);
  }
  __syncthreads();  // B7

  // 128 groups x 8 lanes; lane owns feature slots j8..j8+7 (one uint4 of hb).
  int g = tid >> 3, j8 = (tid & 7) << 3;
  float s = 1.0f + eps[0];

  for (int n = g; n < RSZ; n += 128) {  // 2 iterations
    int node = r * RSZ + n;
    if (node >= N_NODES) continue;  // group-uniform

    float acc[8];
    {  // self term in fp32 (exact residual path)
      const float4 fa = *reinterpret_cast<const float4*>(feat + (node << 6) + j8);
      const float4 fb = *reinterpret_cast<const float4*>(feat + (node << 6) + j8 + 4);
      acc[0] = s * fa.x; acc[1] = s * fa.y; acc[2] = s * fa.z; acc[3] = s * fa.w;
      acc[4] = s * fb.x; acc[5] = s * fb.y; acc[6] = s * fb.z; acc[7] = s * fb.w;
    }

    int e = nstart[n], e1 = nstart[n + 1];
    for (; e + 8 <= e1; e += 8) {
      int i0 = sorted[e + 0], i1 = sorted[e + 1], i2 = sorted[e + 2], i3 = sorted[e + 3];
      int i4_ = sorted[e + 4], i5 = sorted[e + 5], i6 = sorted[e + 6], i7 = sorted[e + 7];
      const uint4 h0 = *reinterpret_cast<const uint4*>(hb + (i0 << 6) + j8);
      const uint4 h1 = *reinterpret_cast<const uint4*>(hb + (i1 << 6) + j8);
      const uint4 h2 = *reinterpret_cast<const uint4*>(hb + (i2 << 6) + j8);
      const uint4 h3 = *reinterpret_cast<const uint4*>(hb + (i3 << 6) + j8);
      const uint4 h4 = *reinterpret_cast<const uint4*>(hb + (i4_ << 6) + j8);
      const uint4 h5 = *reinterpret_cast<const uint4*>(hb + (i5 << 6) + j8);
      const uint4 h6 = *reinterpret_cast<const uint4*>(hb + (i6 << 6) + j8);
      const uint4 h7 = *reinterpret_cast<const uint4*>(hb + (i7 << 6) + j8);
      acc[0] += (bf_lo(h0.x) + bf_lo(h1.x)) + (bf_lo(h2.x) + bf_lo(h3.x))
              + (bf_lo(h4.x) + bf_lo(h5.x)) + (bf_lo(h6.x) + bf_lo(h7.x));
      acc[1] += (bf_hi(h0.x) + bf_hi(h1.x)) + (bf_hi(h2.x) + bf_hi(h3.x))
              + (bf_hi(h4.x) + bf_hi(h5.x)) + (bf_hi(h6.x) + bf_hi(h7.x));
      acc[2] += (bf_lo(h0.y) + bf_lo(h1.y)) + (bf_lo(h2.y) + bf_lo(h3.y))
              + (bf_lo(h4.y) + bf_lo(h5.y)) + (bf_lo(h6.y) + bf_lo(h7.y));
      acc[3] += (bf_hi(h0.y) + bf_hi(h1.y)) + (bf_hi(h2.y) + bf_hi(h3.y))
              + (bf_hi(h4.y) + bf_hi(h5.y)) + (bf_hi(h6.y) + bf_hi(h7.y));
      acc[4] += (bf_lo(h0.z) + bf_lo(h1.z)) + (bf_lo(h2.z) + bf_lo(h3.z))
              + (bf_lo(h4.z) + bf_lo(h5.z)) + (bf_lo(h6.z) + bf_lo(h7.z));
      acc[5] += (bf_hi(h0.z) + bf_hi(h1.z)) + (bf_hi(h2.z) + bf_hi(h3.z))
              + (bf_hi(h4.z) + bf_hi(h5.z)) + (bf_hi(h6.z) + bf_hi(h7.z));
      acc[6] += (bf_lo(h0.w) + bf_lo(h1.w)) + (bf_lo(h2.w) + bf_lo(h3.w))
              + (bf_lo(h4.w) + bf_lo(h5.w)) + (bf_lo(h6.w) + bf_lo(h7.w));
      acc[7] += (bf_hi(h0.w) + bf_hi(h1.w)) + (bf_hi(h2.w) + bf_hi(h3.w))
              + (bf_hi(h4.w) + bf_hi(h5.w)) + (bf_hi(h6.w) + bf_hi(h7.w));
    }
    for (; e < e1; ++e) {
      int sn = sorted[e];
      const uint4 hv = *reinterpret_cast<const uint4*>(hb + (sn << 6) + j8);
      acc[0] += bf_lo(hv.x); acc[1] += bf_hi(hv.x);
      acc[2] += bf_lo(hv.y); acc[3] += bf_hi(hv.y);
      acc[4] += bf_lo(hv.z); acc[5] += bf_hi(hv.z);
      acc[6] += bf_lo(hv.w); acc[7] += bf_hi(hv.w);
    }

    // Matvec: feature i lives in lane (i>>3), slot (i&7) — both constant
    // under full unroll, so acc stays in registers (SROA-safe).
    float res[8];
    {
      const float4 ba = *reinterpret_cast<const float4*>(b + j8);
      const float4 bb = *reinterpret_cast<const float4*>(b + j8 + 4);
      res[0] = ba.x; res[1] = ba.y; res[2] = ba.z; res[3] = ba.w;
      res[4] = bb.x; res[5] = bb.y; res[6] = bb.z; res[7] = bb.w;
    }
#pragma unroll
    for (int i = 0; i < D; ++i) {
      float rv = __shfl(acc[i & 7], i >> 3, 8);  // rst[node][i]
      const float4 wa = *reinterpret_cast<const float4*>(Wt + i * D + j8);
      const float4 wb = *reinterpret_cast<const float4*>(Wt + i * D + j8 + 4);
      res[0] += rv * wa.x; res[1] += rv * wa.y;
      res[2] += rv * wa.z; res[3] += rv * wa.w;
      res[4] += rv * wb.x; res[5] += rv * wb.y;
      res[6] += rv * wb.z; res[7] += rv * wb.w;
    }
    float4 o0, o1;
    o0.x = res[0]; o0.y = res[1]; o0.z = res[2]; o0.w = res[3];
    o1.x = res[4]; o1.y = res[5]; o1.z = res[6]; o1.w = res[7];
    *reinterpret_cast<float4*>(out + (node << 6) + j8) = o0;
    *reinterpret_cast<float4*>(out + (node << 6) + j8 + 4) = o1;
  }
}

extern "C" void kernel_launch(void* const* d_in, const int* in_sizes, int n_in,
                              void* d_out, int out_size, void* d_ws, size_t ws_size,
                              hipStream_t stream) {
  const float* feat = (const float*)d_in[0];
  const float* W    = (const float*)d_in[1];
  const float* b    = (const float*)d_in[2];
  const float* eps  = (const float*)d_in[3];
  const int*   src  = (const int*)d_in[4];
  const int*   dst  = (const int*)d_in[5];
  float* out = (float*)d_out;

  int* ws = (int*)d_ws;
  int* cnt2      = ws + WS_CNT2;
  unsigned* rbuf = (unsigned*)(ws + WS_RBUF);
  ushort* hb     = (ushort*)((char*)d_ws + WS_HB_BYTE);

  hipLaunchKernelGGL(prep_kernel, dim3(NBINB), dim3(1024), 0, stream,
                     (const float4*)feat, src, dst, hb, cnt2, rbuf);
  hipLaunchKernelGGL(gin_kernel, dim3(NREG), dim3(1024), 0, stream,
                     feat, hb, W, b, eps, cnt2, rbuf, out);
}